// Round 8
// baseline (1107.588 us; speedup 1.0000x reference)
//
#include <hip/hip_runtime.h>
#include <hip/hip_bf16.h>
#include <stdint.h>

#define TOKENS 4096
#define IN_F   4096
#define OUT_F  16384
#define NT64   (IN_F / 64)   // 64 K-tiles of BK=64

using f32x4   = __attribute__((ext_vector_type(4))) float;
using bf16x8  = __attribute__((ext_vector_type(8))) short;

// round-to-nearest-even f32 -> bf16 (raw ushort)
static __device__ __forceinline__ ushort f2bf(float f) {
    union { float f; uint32_t u; } v; v.f = f;
    uint32_t u = v.u;
    u += 0x7FFFu + ((u >> 16) & 1u);
    return (ushort)(u >> 16);
}

static __device__ __forceinline__ float tern(float a, float b) {
    float sa = (a > 0.f) ? 1.f : ((a < 0.f) ? -1.f : 0.f);
    float sb = (b > 0.f) ? 1.f : ((b < 0.f) ? -1.f : 0.f);
    return 0.5f * (sa + sb);
}

// ---- preprocessing -----------------------------------------------------------
__global__ __launch_bounds__(256) void k_ternarize(const float4* __restrict__ w1,
                                                   const float4* __restrict__ w2,
                                                   ushort* __restrict__ wb, int n4) {
    int idx = blockIdx.x * blockDim.x + threadIdx.x;
    int stride = gridDim.x * blockDim.x;
    for (int i = idx; i < n4; i += stride) {
        float4 a = w1[i], b = w2[i];
        ushort4 o;
        o.x = f2bf(tern(a.x, b.x));
        o.y = f2bf(tern(a.y, b.y));
        o.z = f2bf(tern(a.z, b.z));
        o.w = f2bf(tern(a.w, b.w));
        reinterpret_cast<ushort4*>(wb)[i] = o;
    }
}

__global__ __launch_bounds__(256) void k_xconv(const float4* __restrict__ x,
                                               ushort* __restrict__ xb, int n4) {
    int idx = blockIdx.x * blockDim.x + threadIdx.x;
    int stride = gridDim.x * blockDim.x;
    for (int i = idx; i < n4; i += stride) {
        float4 a = x[i];
        ushort4 o;
        o.x = f2bf(a.x); o.y = f2bf(a.y); o.z = f2bf(a.z); o.w = f2bf(a.w);
        reinterpret_cast<ushort4*>(xb)[i] = o;
    }
}

// ---- helpers -----------------------------------------------------------------
#define GLDS(gp, lp) __builtin_amdgcn_global_load_lds(                          \
    (const __attribute__((address_space(1))) uint32_t*)(gp),                    \
    (__attribute__((address_space(3))) uint32_t*)(lp), 16, 0, 0)

// LDS XOR swizzle within a [64|32 rows][64B] sub-block: flip byte bits [5:4]
// with row bits [2:1]. Involution on 16B chunks; measured conflict-free for the
// 16-row ds_read_b128 fragment pattern (rounds 2/3/5/6: SQ_LDS_BANK_CONFLICT=0).
#define SWZ(z) ((z) ^ ((((z) >> 7) & 3) << 4))

#define WAITV(n) __asm__ __volatile__("s_waitcnt vmcnt(" #n ")")
#define WAITL0() __asm__ __volatile__("s_waitcnt lgkmcnt(0)")
#define BAR()    __builtin_amdgcn_s_barrier()
#define SCHED0() __builtin_amdgcn_sched_barrier(0)

// ---- main GEMM: 256x256 tile, BK=64, dbuf-2 (128KB), 4 fine phases/K-tile ----
// C[M,N] = A[M,K](bf16) * B[N,K](bf16)^T + bias, 16x16x32 MFMA.
// Buffer layout (64KB): Alo@0, Ahi@16K, Blo@32K, Bhi@48K.
//   A granule: [wm:2][kh:2][4KB = 64 rows x 64B swizzled]
//     Alo rows: wm*128+[0,64); Ahi: wm*128+[64,128)
//   B granule: [wn:4][kh:2][2KB = 32 rows x 64B swizzled]
//     Blo rows: wn*64+[0,32); Bhi: wn*64+[32,64)
// Per K-tile, 4 phases; each: {ds_reads | 2 staging gloads | vmcnt(4) | BAR |
//   lgkm(0) | setprio(1) 16 MFMA setprio(0)}.
// Staging: p1:Ahi(T+1)->ob, p2:Bhi(T+1)->ob, p3:Alo(T+2)->bb, p4:Blo(T+2)->bb.
// FIFO cert: every granule drains via vmcnt(4) >=2 phases before first read.
// p3/p4 write regions of bb read only at p1 (all waves past p2 BAR => done).
__global__ __launch_bounds__(512, 2) void k_gemm8p(const ushort* __restrict__ A,
                                                   const ushort* __restrict__ B,
                                                   const float* __restrict__ bias,
                                                   float* __restrict__ C) {
    extern __shared__ __align__(16) char smem[];   // 2 x 64KB

    const int tid  = threadIdx.x;
    const int lane = tid & 63;
    const int wave = tid >> 6;
    const int wm = wave >> 2;      // 0..1
    const int wn = wave & 3;       // 0..3
    const int lr = lane & 15;
    const int hk = lane >> 4;      // 0..3

    // XCD-aware swizzle (1024 blocks, 1024%8==0)
    const int bid = blockIdx.x;
    const int wgp = (bid & 7) * 128 + (bid >> 3);
    const int mBase = (wgp & 15) * 256;
    const int nBase = (wgp >> 4) * 256;

    // ds_read byte offsets (within granule)
    int zA[4][2], zB[2][2];
#pragma unroll
    for (int mi = 0; mi < 4; ++mi)
#pragma unroll
        for (int kh = 0; kh < 2; ++kh)
            zA[mi][kh] = wm * 8192 + kh * 4096 + SWZ((mi * 16 + lr) * 64 + hk * 16);
#pragma unroll
    for (int nb = 0; nb < 2; ++nb)
#pragma unroll
        for (int kh = 0; kh < 2; ++kh)
            zB[nb][kh] = wn * 4096 + kh * 2048 + SWZ((nb * 16 + lr) * 64 + hk * 16);

    // staging sources: inverse-swizzled global positions (rule #21)
    auto soffA = [](int q) -> size_t {
        int z = q * 16;
        int wmg = z >> 13, kh = (z >> 12) & 1;
        int zs = SWZ(z & 4095);
        return (size_t)(wmg * 128 + (zs >> 6)) * IN_F + kh * 32 + ((zs & 63) >> 1);
    };
    auto soffB = [](int q) -> size_t {
        int z = q * 16;
        int wng = z >> 12, kh = (z >> 11) & 1;
        int zs = SWZ(z & 2047);
        return (size_t)(wng * 64 + (zs >> 6)) * IN_F + kh * 32 + ((zs & 63) >> 1);
    };
    const ushort* pA[2][2];
    const ushort* pB[2][2];
#pragma unroll
    for (int c = 0; c < 2; ++c) {
        pA[0][c] = A + (size_t)mBase * IN_F + soffA(tid + 512 * c);         // Alo
        pA[1][c] = A + (size_t)(mBase + 64) * IN_F + soffA(tid + 512 * c);  // Ahi
        pB[0][c] = B + (size_t)nBase * IN_F + soffB(tid + 512 * c);         // Blo
        pB[1][c] = B + (size_t)(nBase + 32) * IN_F + soffB(tid + 512 * c);  // Bhi
    }

    char* const bufs[2] = { smem, smem + 65536 };

#define STG_A(bb, h, tt) do {                                                   \
    GLDS(pA[h][0] + (size_t)(tt) * 64, (bb) + (h) * 16384 + tid * 16);          \
    GLDS(pA[h][1] + (size_t)(tt) * 64, (bb) + (h) * 16384 + 8192 + tid * 16);   \
} while (0)
#define STG_B(bb, h, tt) do {                                                   \
    GLDS(pB[h][0] + (size_t)(tt) * 64, (bb) + 32768 + (h) * 16384 + tid * 16);  \
    GLDS(pB[h][1] + (size_t)(tt) * 64, (bb) + 32768 + (h) * 16384 + 8192 + tid * 16); \
} while (0)

    f32x4 acc[8][4] = {};

    // prologue: T0 all 4 granules + T1 Alo,Blo  (12 loads)
    STG_A(bufs[0], 0, 0);
    STG_B(bufs[0], 0, 0);
    STG_A(bufs[0], 1, 0);
    STG_B(bufs[0], 1, 0);
    STG_A(bufs[1], 0, 1);
    STG_B(bufs[1], 0, 1);
    WAITV(4);        // T0 fully landed; T1's Alo/Blo in flight
    BAR();
    SCHED0();

#define TILE(TT, POS, S12, S34, W4) do {                                        \
    char* bb = bufs[(POS)];                                                     \
    char* ob = bufs[(POS) ^ 1];                                                 \
    bf16x8 alo[4][2], ahi[4][2], blo[2][2], bhi[2][2];                          \
    /* ---- phase 1: read Alo+Blo (12); stage Ahi(T+1)->ob ---- */              \
    _Pragma("unroll") for (int mi = 0; mi < 4; ++mi)                            \
        _Pragma("unroll") for (int kh = 0; kh < 2; ++kh)                        \
            alo[mi][kh] = *(const bf16x8*)(bb + zA[mi][kh]);                    \
    _Pragma("unroll") for (int nb = 0; nb < 2; ++nb)                            \
        _Pragma("unroll") for (int kh = 0; kh < 2; ++kh)                        \
            blo[nb][kh] = *(const bf16x8*)(bb + 32768 + zB[nb][kh]);            \
    if (S12) STG_A(ob, 1, (TT) + 1);                                            \
    SCHED0(); WAITV(4); BAR(); WAITL0(); SCHED0();                              \
    __builtin_amdgcn_s_setprio(1);                                              \
    _Pragma("unroll") for (int kh = 0; kh < 2; ++kh)                            \
        _Pragma("unroll") for (int mi = 0; mi < 4; ++mi)                        \
            _Pragma("unroll") for (int nj = 0; nj < 2; ++nj)                    \
                acc[mi][nj] = __builtin_amdgcn_mfma_f32_16x16x32_bf16(          \
                    alo[mi][kh], blo[nj][kh], acc[mi][nj], 0, 0, 0);            \
    __builtin_amdgcn_s_setprio(0); SCHED0();                                    \
    /* ---- phase 2: read Ahi (8); stage Bhi(T+1)->ob ---- */                   \
    _Pragma("unroll") for (int mi = 0; mi < 4; ++mi)                            \
        _Pragma("unroll") for (int kh = 0; kh < 2; ++kh)                        \
            ahi[mi][kh] = *(const bf16x8*)(bb + 16384 + zA[mi][kh]);            \
    if (S12) STG_B(ob, 1, (TT) + 1);                                            \
    SCHED0(); WAITV(4); BAR(); WAITL0(); SCHED0();                              \
    __builtin_amdgcn_s_setprio(1);                                              \
    _Pragma("unroll") for (int kh = 0; kh < 2; ++kh)                            \
        _Pragma("unroll") for (int mi = 0; mi < 4; ++mi)                        \
            _Pragma("unroll") for (int nj = 0; nj < 2; ++nj)                    \
                acc[4 + mi][nj] = __builtin_amdgcn_mfma_f32_16x16x32_bf16(      \
                    ahi[mi][kh], blo[nj][kh], acc[4 + mi][nj], 0, 0, 0);        \
    __builtin_amdgcn_s_setprio(0); SCHED0();                                    \
    /* ---- phase 3: read Bhi (4); stage Alo(T+2)->bb (region dead) ---- */     \
    _Pragma("unroll") for (int nb = 0; nb < 2; ++nb)                            \
        _Pragma("unroll") for (int kh = 0; kh < 2; ++kh)                        \
            bhi[nb][kh] = *(const bf16x8*)(bb + 49152 + zB[nb][kh]);            \
    if (S34) STG_A(bb, 0, (TT) + 2);                                            \
    SCHED0(); WAITV(4); BAR(); WAITL0(); SCHED0();                              \
    __builtin_amdgcn_s_setprio(1);                                              \
    _Pragma("unroll") for (int kh = 0; kh < 2; ++kh)                            \
        _Pragma("unroll") for (int mi = 0; mi < 4; ++mi)                        \
            _Pragma("unroll") for (int nj = 0; nj < 2; ++nj)                    \
                acc[4 + mi][2 + nj] = __builtin_amdgcn_mfma_f32_16x16x32_bf16(  \
                    ahi[mi][kh], bhi[nj][kh], acc[4 + mi][2 + nj], 0, 0, 0);    \
    __builtin_amdgcn_s_setprio(0); SCHED0();                                    \
    /* ---- phase 4: no reads; stage Blo(T+2)->bb ---- */                       \
    if (S34) STG_B(bb, 0, (TT) + 2);                                            \
    SCHED0(); W4; BAR(); SCHED0();                                              \
    __builtin_amdgcn_s_setprio(1);                                              \
    _Pragma("unroll") for (int kh = 0; kh < 2; ++kh)                            \
        _Pragma("unroll") for (int mi = 0; mi < 4; ++mi)                        \
            _Pragma("unroll") for (int nj = 0; nj < 2; ++nj)                    \
                acc[mi][2 + nj] = __builtin_amdgcn_mfma_f32_16x16x32_bf16(      \
                    alo[mi][kh], bhi[nj][kh], acc[mi][2 + nj], 0, 0, 0);        \
    __builtin_amdgcn_s_setprio(0); SCHED0();                                    \
} while (0)

#pragma unroll 1
    for (int T0 = 0; T0 < NT64 - 2; T0 += 2) {   // tiles 0..61, full staging
        TILE(T0, 0, 1, 1, WAITV(4));
        TILE(T0 + 1, 1, 1, 1, WAITV(4));
    }
    TILE(NT64 - 2, 0, 1, 0, WAITV(0));   // tile 62: stage Ahi/Bhi(63); drain
    TILE(NT64 - 1, 1, 0, 0, ((void)0));  // tile 63: no staging
#undef TILE
#undef STG_A
#undef STG_B

    // epilogue: C/D layout col = lane&15, row = (lane>>4)*4 + reg
#pragma unroll
    for (int i = 0; i < 8; ++i) {
        const int row = mBase + wm * 128 + i * 16 + hk * 4;
#pragma unroll
        for (int j = 0; j < 4; ++j) {
            const int col = nBase + wn * 64 + j * 16 + lr;
            const float bv = bias[col];
#pragma unroll
            for (int q = 0; q < 4; ++q)
                C[(size_t)(row + q) * OUT_F + col] = acc[i][j][q] + bv;
        }
    }
}

// ---- round-1 128^2 kernel kept as fallback (static 32KB LDS) -----------------
__global__ __launch_bounds__(256, 2) void k_gemm(const ushort* __restrict__ A,
                                                 const ushort* __restrict__ B,
                                                 const float* __restrict__ bias,
                                                 float* __restrict__ C) {
    __shared__ __align__(16) ushort lA[128 * 32];
    __shared__ __align__(16) ushort lB[128 * 32];
    const int tid  = threadIdx.x;
    const int lane = tid & 63;
    const int wave = tid >> 6;
    const int wm = wave >> 1, wn = wave & 1;
    const int mBase = blockIdx.y * 128, nBase = blockIdx.x * 128;
    const int lr = lane & 15, lk = (lane >> 4) * 8;
    f32x4 acc[4][4] = {};
    const int sr = tid >> 2, ss = (tid & 3) * 8;
    const ushort* gA0 = A + (size_t)(mBase + sr) * IN_F + ss;
    const ushort* gA1 = A + (size_t)(mBase + 64 + sr) * IN_F + ss;
    const ushort* gB0 = B + (size_t)(nBase + sr) * IN_F + ss;
    const ushort* gB1 = B + (size_t)(nBase + 64 + sr) * IN_F + ss;
    char* laByte = (char*)lA;
    char* lbByte = (char*)lB;
    for (int k0 = 0; k0 < IN_F; k0 += 32) {
        GLDS(gA0 + k0, laByte + tid * 16);
        GLDS(gA1 + k0, laByte + 4096 + tid * 16);
        GLDS(gB0 + k0, lbByte + tid * 16);
        GLDS(gB1 + k0, lbByte + 4096 + tid * 16);
        __syncthreads();
        bf16x8 af[4], bg[4];
#pragma unroll
        for (int i = 0; i < 4; ++i) af[i] = *(const bf16x8*)&lA[(wm * 64 + i * 16 + lr) * 32 + lk];
#pragma unroll
        for (int j = 0; j < 4; ++j) bg[j] = *(const bf16x8*)&lB[(wn * 64 + j * 16 + lr) * 32 + lk];
#pragma unroll
        for (int i = 0; i < 4; ++i)
#pragma unroll
            for (int j = 0; j < 4; ++j)
                acc[i][j] = __builtin_amdgcn_mfma_f32_16x16x32_bf16(af[i], bg[j], acc[i][j], 0, 0, 0);
        __syncthreads();
    }
#pragma unroll
    for (int i = 0; i < 4; ++i) {
        const int row = mBase + wm * 64 + i * 16 + (lane >> 4) * 4;
#pragma unroll
        for (int j = 0; j < 4; ++j) {
            const int col = nBase + wn * 64 + j * 16 + lr;
            const float bv = bias[col];
#pragma unroll
            for (int q = 0; q < 4; ++q)
                C[(size_t)(row + q) * OUT_F + col] = acc[i][j][q] + bv;
        }
    }
}

// ---- fp32 fallback if ws too small ------------------------------------------
__global__ __launch_bounds__(256) void k_fallback(const float* __restrict__ x,
                                                  const float* __restrict__ w1,
                                                  const float* __restrict__ w2,
                                                  const float* __restrict__ bias,
                                                  float* __restrict__ C) {
    __shared__ float sx[64][17];
    __shared__ float sw[64][17];
    const int tid = threadIdx.x;
    const int mb = blockIdx.y * 64, nb = blockIdx.x * 64;
    const int ty = tid >> 4, tx = tid & 15;
    float acc[4][4] = {};
    const int r = tid >> 2, s = (tid & 3) * 4;
    for (int k0 = 0; k0 < IN_F; k0 += 16) {
        float4 xv = *(const float4*)&x[(size_t)(mb + r) * IN_F + k0 + s];
        float4 a1 = *(const float4*)&w1[(size_t)(nb + r) * IN_F + k0 + s];
        float4 a2 = *(const float4*)&w2[(size_t)(nb + r) * IN_F + k0 + s];
        sx[r][s + 0] = xv.x; sx[r][s + 1] = xv.y; sx[r][s + 2] = xv.z; sx[r][s + 3] = xv.w;
        sw[r][s + 0] = tern(a1.x, a2.x); sw[r][s + 1] = tern(a1.y, a2.y);
        sw[r][s + 2] = tern(a1.z, a2.z); sw[r][s + 3] = tern(a1.w, a2.w);
        __syncthreads();
#pragma unroll
        for (int kk = 0; kk < 16; ++kk) {
            float av[4], bv[4];
#pragma unroll
            for (int i = 0; i < 4; ++i) av[i] = sx[ty * 4 + i][kk];
#pragma unroll
            for (int j = 0; j < 4; ++j) bv[j] = sw[tx * 4 + j][kk];
#pragma unroll
            for (int i = 0; i < 4; ++i)
#pragma unroll
                for (int j = 0; j < 4; ++j) acc[i][j] += av[i] * bv[j];
        }
        __syncthreads();
    }
#pragma unroll
    for (int i = 0; i < 4; ++i)
#pragma unroll
        for (int j = 0; j < 4; ++j)
            C[(size_t)(mb + ty * 4 + i) * OUT_F + nb + tx * 4 + j] = acc[i][j] + bias[nb + tx * 4 + j];
}

extern "C" void kernel_launch(void* const* d_in, const int* in_sizes, int n_in,
                              void* d_out, int out_size, void* d_ws, size_t ws_size,
                              hipStream_t stream) {
    const float* x    = (const float*)d_in[0];
    const float* w1   = (const float*)d_in[1];
    const float* w2   = (const float*)d_in[2];
    const float* bias = (const float*)d_in[3];
    float* out = (float*)d_out;

    const size_t need = ((size_t)TOKENS * IN_F + (size_t)OUT_F * IN_F) * sizeof(ushort);
    if (ws_size >= need) {
        ushort* xb = (ushort*)d_ws;
        ushort* wb = xb + (size_t)TOKENS * IN_F;
        k_xconv<<<1024, 256, 0, stream>>>((const float4*)x, xb, TOKENS * IN_F / 4);
        k_ternarize<<<2048, 256, 0, stream>>>((const float4*)w1, (const float4*)w2, wb,
                                              OUT_F * IN_F / 4);
        hipError_t e = hipFuncSetAttribute((const void*)k_gemm8p,
                                           hipFuncAttributeMaxDynamicSharedMemorySize, 131072);
        if (e == hipSuccess) {
            k_gemm8p<<<dim3(1024), 512, 131072, stream>>>(xb, wb, bias, out);
        } else {
            dim3 grid(OUT_F / 128, TOKENS / 128);
            k_gemm<<<grid, 256, 0, stream>>>(xb, wb, bias, out);
        }
    } else {
        dim3 grid(OUT_F / 64, TOKENS / 64);
        k_fallback<<<grid, 256, 0, stream>>>(x, w1, w2, bias, out);
    }
}

// Round 9
// 454.226 us; speedup vs baseline: 2.4384x; 2.4384x over previous
//
#include <hip/hip_runtime.h>
#include <hip/hip_bf16.h>
#include <stdint.h>

#define TOKENS 4096
#define IN_F   4096
#define OUT_F  16384
#define NT     (IN_F / 64)   // 64 K-tiles of BK=64 (i8)

#define QSCALE (6.0f / 127.0f)   // dequant scale
#define QINV   (127.0f / 6.0f)   // quant scale

using i32x4  = __attribute__((ext_vector_type(4))) int;
using f32x4  = __attribute__((ext_vector_type(4))) float;

// ---- preprocessing: quantize x -> i8, ternarize w1,w2 -> i8 ------------------
__global__ __launch_bounds__(256) void k_xquant(const float4* __restrict__ x,
                                                int4* __restrict__ xb, int n16) {
    int idx = blockIdx.x * blockDim.x + threadIdx.x;
    int stride = gridDim.x * blockDim.x;
    for (int i = idx; i < n16; i += stride) {
        union { signed char c[16]; int4 v; } u;
#pragma unroll
        for (int j = 0; j < 4; ++j) {
            float4 a = x[i * 4 + j];
            float vals[4] = { a.x, a.y, a.z, a.w };
#pragma unroll
            for (int e = 0; e < 4; ++e) {
                int q = __float2int_rn(vals[e] * QINV);
                q = q > 127 ? 127 : (q < -127 ? -127 : q);
                u.c[j * 4 + e] = (signed char)q;
            }
        }
        xb[i] = u.v;
    }
}

__global__ __launch_bounds__(256) void k_ternarize(const float4* __restrict__ w1,
                                                   const float4* __restrict__ w2,
                                                   int4* __restrict__ wb, int n16) {
    int idx = blockIdx.x * blockDim.x + threadIdx.x;
    int stride = gridDim.x * blockDim.x;
    for (int i = idx; i < n16; i += stride) {
        union { signed char c[16]; int4 v; } u;
#pragma unroll
        for (int j = 0; j < 4; ++j) {
            float4 a = w1[i * 4 + j];
            float4 b = w2[i * 4 + j];
            float av[4] = { a.x, a.y, a.z, a.w };
            float bv[4] = { b.x, b.y, b.z, b.w };
#pragma unroll
            for (int e = 0; e < 4; ++e) {
                int s = ((av[e] > 0.f) - (av[e] < 0.f)) + ((bv[e] > 0.f) - (bv[e] < 0.f));
                u.c[j * 4 + e] = (signed char)(s / 2);   // {-1, 0, +1}
            }
        }
        wb[i] = u.v;
    }
}

// ---- helpers -----------------------------------------------------------------
#define GLDS(gp, lp) __builtin_amdgcn_global_load_lds(                          \
    (const __attribute__((address_space(1))) uint32_t*)(gp),                    \
    (__attribute__((address_space(3))) uint32_t*)(lp), 16, 0, 0)

// LDS XOR swizzle: flip byte bits [5:4] with row bits [2:1] (z bits [8:7]).
// Involution on 16B chunks; measured conflict-free for the 16-row ds_read_b128
// fragment pattern (rounds 2/3/5/6: SQ_LDS_BANK_CONFLICT == 0). Byte-identical
// geometry to the bf16 BK=32 kernel: rows are 64B (now 64 i8 instead of 32 bf16).
#define SWZ(z) ((z) ^ ((((z) >> 7) & 3) << 4))

#define WAITV(n) __asm__ __volatile__("s_waitcnt vmcnt(" #n ")")
#define WAITL0() __asm__ __volatile__("s_waitcnt lgkmcnt(0)")
#define BAR()    __builtin_amdgcn_s_barrier()
#define SCHED0() __builtin_amdgcn_sched_barrier(0)

// ---- main GEMM: 256x256 tile, BK=64 i8, static ring-4 LDS, counted vmcnt -----
// C[M,N] = (A[M,K]i8 * B[N,K]i8^T) * QSCALE + bias, 16x16x64 i8 MFMA.
// Structure == round-5 bf16 kernel (best measured); only dtype/K-depth changed.
__global__ __launch_bounds__(512, 2) void k_gemmi8(const signed char* __restrict__ A,
                                                   const signed char* __restrict__ B,
                                                   const float* __restrict__ bias,
                                                   float* __restrict__ C) {
    extern __shared__ __align__(16) char smem[];   // 4 bufs x (A 16KB + B 16KB) = 128KB

    const int tid  = threadIdx.x;
    const int lane = tid & 63;
    const int wave = tid >> 6;
    const int wm = wave >> 2;      // 0..1  (M half)
    const int wn = wave & 3;       // 0..3  (N quarter)
    const int lr = lane & 15;
    const int hk = lane >> 4;      // 0..3

    // XCD-aware swizzle: XCD x owns wgp in [x*128,(x+1)*128) (1024 % 8 == 0)
    const int bid = blockIdx.x;
    const int wgp = (bid & 7) * 128 + (bid >> 3);
    const int mBase = (wgp & 15) * 256;
    const int nBase = (wgp >> 4) * 256;

    // swizzled ds_read offsets (bytes within buffer region); rows are 64B
    int zA[8], zB[4];
#pragma unroll
    for (int i = 0; i < 8; ++i) {
        int z = (wm * 128 + i * 16 + lr) * 64 + hk * 16;
        zA[i] = SWZ(z);
    }
#pragma unroll
    for (int j = 0; j < 4; ++j) {
        int z = (wn * 64 + j * 16 + lr) * 64 + hk * 16;
        zB[j] = SWZ(z);
    }

    // staging: linear LDS dest chunks q0,q1; global source inverse-swizzled
    const int q0 = tid, q1 = tid + 512;
    auto soff = [](int q) -> size_t {   // byte offset within a [rows][IN_F] i8 panel
        int z  = q * 16;
        int zs = SWZ(z);
        return (size_t)(zs >> 6) * IN_F + (size_t)(zs & 63);
    };
    const signed char* gA0 = A + (size_t)mBase * IN_F + soff(q0);
    const signed char* gA1 = A + (size_t)mBase * IN_F + soff(q1);
    const signed char* gB0 = B + (size_t)nBase * IN_F + soff(q0);
    const signed char* gB1 = B + (size_t)nBase * IN_F + soff(q1);

    char* const bufs[4] = { smem, smem + 32768, smem + 65536, smem + 98304 };

    i32x4 acc[8][4] = {};

    // prologue: stage tiles 0,1,2 (12 loads/thread in flight); K-advance = 64B
#pragma unroll
    for (int t = 0; t < 3; ++t) {
        char* bb = bufs[t];
        GLDS(gA0 + (size_t)t * 64, bb + q0 * 16);
        GLDS(gA1 + (size_t)t * 64, bb + q1 * 16);
        GLDS(gB0 + (size_t)t * 64, bb + 16384 + q0 * 16);
        GLDS(gB1 + (size_t)t * 64, bb + 16384 + q1 * 16);
    }
    WAITV(8);        // tile 0 landed; tiles 1,2 still in flight
    BAR();
    SCHED0();

    // One K-tile: 2 fence-disciplined phases; counted vmcnt at tile end.
#define TILE(TT, POS, DOSTAGE, WN) do {                                         \
    char* bufA = bufs[(POS)];                                                   \
    char* bufB = bufA + 16384;                                                  \
    char* sb   = bufs[((POS) + 3) & 3];                                         \
    i32x4 a0[4], bfr[4], a1[4];                                                 \
    /* ---- phase 0: read a0[4]+bfr[4], stage next-A ---- */                    \
    _Pragma("unroll")                                                           \
    for (int i = 0; i < 4; ++i) a0[i] = *(const i32x4*)(bufA + zA[i]);          \
    _Pragma("unroll")                                                           \
    for (int j = 0; j < 4; ++j) bfr[j] = *(const i32x4*)(bufB + zB[j]);         \
    if (DOSTAGE) {                                                              \
        GLDS(gA0 + (size_t)((TT) + 3) * 64, sb + q0 * 16);                      \
        GLDS(gA1 + (size_t)((TT) + 3) * 64, sb + q1 * 16);                      \
    }                                                                           \
    SCHED0();                                                                   \
    BAR();                                                                      \
    WAITL0();                                                                   \
    SCHED0();                                                                   \
    __builtin_amdgcn_s_setprio(1);                                              \
    _Pragma("unroll")                                                           \
    for (int i = 0; i < 4; ++i)                                                 \
        _Pragma("unroll")                                                       \
        for (int j = 0; j < 4; ++j)                                             \
            acc[i][j] = __builtin_amdgcn_mfma_i32_16x16x64_i8(a0[i], bfr[j],    \
                                                              acc[i][j], 0, 0, 0); \
    __builtin_amdgcn_s_setprio(0);                                              \
    SCHED0();                                                                   \
    BAR();                                                                      \
    /* ---- phase 1: read a1[4], stage next-B ---- */                           \
    _Pragma("unroll")                                                           \
    for (int i = 0; i < 4; ++i) a1[i] = *(const i32x4*)(bufA + zA[4 + i]);      \
    if (DOSTAGE) {                                                              \
        GLDS(gB0 + (size_t)((TT) + 3) * 64, sb + 16384 + q0 * 16);              \
        GLDS(gB1 + (size_t)((TT) + 3) * 64, sb + 16384 + q1 * 16);              \
    }                                                                           \
    SCHED0();                                                                   \
    BAR();                                                                      \
    WAITL0();                                                                   \
    SCHED0();                                                                   \
    __builtin_amdgcn_s_setprio(1);                                              \
    _Pragma("unroll")                                                           \
    for (int i = 0; i < 4; ++i)                                                 \
        _Pragma("unroll")                                                       \
        for (int j = 0; j < 4; ++j)                                             \
            acc[4 + i][j] = __builtin_amdgcn_mfma_i32_16x16x64_i8(a1[i], bfr[j],\
                                                                  acc[4 + i][j], 0, 0, 0); \
    __builtin_amdgcn_s_setprio(0);                                              \
    WN;                                                                         \
    SCHED0();                                                                   \
    BAR();                                                                      \
} while (0)

#pragma unroll 1
    for (int T0 = 0; T0 < NT - 4; T0 += 4) {   // tiles 0..59, always staging
        TILE(T0 + 0, 0, 1, WAITV(8));
        TILE(T0 + 1, 1, 1, WAITV(8));
        TILE(T0 + 2, 2, 1, WAITV(8));
        TILE(T0 + 3, 3, 1, WAITV(8));
    }
    // tail: tiles 60..63 — stage last tile, then drain 8 -> 4 -> 0
    TILE(NT - 4, 0, 1, WAITV(8));
    TILE(NT - 3, 1, 0, WAITV(4));
    TILE(NT - 2, 2, 0, WAITV(0));
    TILE(NT - 1, 3, 0, ((void)0));
#undef TILE

    // epilogue: C/D layout col = lane&15, row = (lane>>4)*4 + reg; dequant
#pragma unroll
    for (int i = 0; i < 8; ++i) {
        const int row = mBase + wm * 128 + i * 16 + hk * 4;
#pragma unroll
        for (int j = 0; j < 4; ++j) {
            const int col = nBase + wn * 64 + j * 16 + lr;
            const float bv = bias[col];
#pragma unroll
            for (int q = 0; q < 4; ++q)
                C[(size_t)(row + q) * OUT_F + col] = (float)acc[i][j][q] * QSCALE + bv;
        }
    }
}

// ---- fp32 fallback (ws too small or attribute failure) -----------------------
static __device__ __forceinline__ float tern(float a, float b) {
    float sa = (a > 0.f) ? 1.f : ((a < 0.f) ? -1.f : 0.f);
    float sb = (b > 0.f) ? 1.f : ((b < 0.f) ? -1.f : 0.f);
    return 0.5f * (sa + sb);
}

__global__ __launch_bounds__(256) void k_fallback(const float* __restrict__ x,
                                                  const float* __restrict__ w1,
                                                  const float* __restrict__ w2,
                                                  const float* __restrict__ bias,
                                                  float* __restrict__ C) {
    __shared__ float sx[64][17];
    __shared__ float sw[64][17];
    const int tid = threadIdx.x;
    const int mb = blockIdx.y * 64, nb = blockIdx.x * 64;
    const int ty = tid >> 4, tx = tid & 15;
    float acc[4][4] = {};
    const int r = tid >> 2, s = (tid & 3) * 4;
    for (int k0 = 0; k0 < IN_F; k0 += 16) {
        float4 xv = *(const float4*)&x[(size_t)(mb + r) * IN_F + k0 + s];
        float4 a1 = *(const float4*)&w1[(size_t)(nb + r) * IN_F + k0 + s];
        float4 a2 = *(const float4*)&w2[(size_t)(nb + r) * IN_F + k0 + s];
        sx[r][s + 0] = xv.x; sx[r][s + 1] = xv.y; sx[r][s + 2] = xv.z; sx[r][s + 3] = xv.w;
        sw[r][s + 0] = tern(a1.x, a2.x); sw[r][s + 1] = tern(a1.y, a2.y);
        sw[r][s + 2] = tern(a1.z, a2.z); sw[r][s + 3] = tern(a1.w, a2.w);
        __syncthreads();
#pragma unroll
        for (int kk = 0; kk < 16; ++kk) {
            float av[4], bv[4];
#pragma unroll
            for (int i = 0; i < 4; ++i) av[i] = sx[ty * 4 + i][kk];
#pragma unroll
            for (int j = 0; j < 4; ++j) bv[j] = sw[tx * 4 + j][kk];
#pragma unroll
            for (int i = 0; i < 4; ++i)
#pragma unroll
                for (int j = 0; j < 4; ++j) acc[i][j] += av[i] * bv[j];
        }
        __syncthreads();
    }
#pragma unroll
    for (int i = 0; i < 4; ++i)
#pragma unroll
        for (int j = 0; j < 4; ++j)
            C[(size_t)(mb + ty * 4 + i) * OUT_F + nb + tx * 4 + j] = acc[i][j] + bias[nb + tx * 4 + j];
}

extern "C" void kernel_launch(void* const* d_in, const int* in_sizes, int n_in,
                              void* d_out, int out_size, void* d_ws, size_t ws_size,
                              hipStream_t stream) {
    const float* x    = (const float*)d_in[0];
    const float* w1   = (const float*)d_in[1];
    const float* w2   = (const float*)d_in[2];
    const float* bias = (const float*)d_in[3];
    float* out = (float*)d_out;

    const size_t need = (size_t)TOKENS * IN_F + (size_t)OUT_F * IN_F;   // i8 bytes
    bool ok = false;
    if (ws_size >= need) {
        signed char* xb = (signed char*)d_ws;
        signed char* wb = xb + (size_t)TOKENS * IN_F;
        hipError_t e = hipFuncSetAttribute((const void*)k_gemmi8,
                                           hipFuncAttributeMaxDynamicSharedMemorySize, 131072);
        if (e == hipSuccess) {
            k_xquant<<<512, 256, 0, stream>>>((const float4*)x, (int4*)xb,
                                              TOKENS * IN_F / 16);
            k_ternarize<<<2048, 256, 0, stream>>>((const float4*)w1, (const float4*)w2,
                                                  (int4*)wb, OUT_F * IN_F / 16);
            k_gemmi8<<<dim3(1024), 512, 131072, stream>>>(xb, wb, bias, out);
            ok = true;
        }
    }
    if (!ok) {
        dim3 grid(OUT_F / 64, TOKENS / 64);
        k_fallback<<<grid, 256, 0, stream>>>(x, w1, w2, bias, out);
    }
}